// Round 3
// baseline (2266.863 us; speedup 1.0000x reference)
//
#include <hip/hip_runtime.h>
#include <stdint.h>

// Problem constants
#define NVOX   221184      // 2*48*48*48 voxels
#define NSTATE 7077888     // NVOX * 32 channels
// ws layout (floats):
//   [0, NSTATE)            stateA (f32)
//   [NSTATE, 2*NSTATE)     stateB (f32)
//   [2*NSTATE, +W_TOT)     weights (f32, transformed layouts)
//   [2*NSTATE + W_TOT]     dtype flag (u32: 1 = inputs are bf16-u16, 0 = f32)
#define W_CWT 0
#define W_CB  6912
#define W_F0W 6928
#define W_F0B 13072
#define W_F1T 13200
#define W_TOT 17296

// ---------- bf16 helpers ----------
__host__ __device__ __forceinline__ float bf2f(unsigned short u) {
  union { uint32_t u; float f; } v; v.u = ((uint32_t)u) << 16; return v.f;
}
__device__ __forceinline__ unsigned short f2bf(float f) {  // RNE, finite values
  union { float f; uint32_t u; } v; v.f = f;
  uint32_t r = (v.u + 0x7FFFu + ((v.u >> 16) & 1u)) >> 16;
  return (unsigned short)r;
}
// dtype-flag-dispatched input load (flag is wave-uniform -> no divergence cost)
__device__ __forceinline__ float ldin(const void* p, int i, uint32_t bf) {
  return bf ? bf2f(((const unsigned short*)p)[i]) : ((const float*)p)[i];
}

// ---------- JAX Threefry-2x32 (20 rounds), bit-exact ----------
__host__ __device__ __forceinline__ void tf2x32(uint32_t k0, uint32_t k1,
                                                uint32_t x0, uint32_t x1,
                                                uint32_t& o0, uint32_t& o1) {
  uint32_t ks2 = k0 ^ k1 ^ 0x1BD11BDAu;
#define TFR(r) { x0 += x1; x1 = (x1 << r) | (x1 >> (32 - r)); x1 ^= x0; }
  x0 += k0; x1 += k1;
  TFR(13) TFR(15) TFR(26) TFR(6)
  x0 += k1;  x1 += ks2 + 1u;
  TFR(17) TFR(29) TFR(16) TFR(24)
  x0 += ks2; x1 += k0 + 2u;
  TFR(13) TFR(15) TFR(26) TFR(6)
  x0 += k0;  x1 += k1 + 3u;
  TFR(17) TFR(29) TFR(16) TFR(24)
  x0 += k1;  x1 += ks2 + 4u;
  TFR(13) TFR(15) TFR(26) TFR(6)
  x0 += ks2; x1 += k0 + 5u;
#undef TFR
  o0 = x0; o1 = x1;
}

// mask for voxel vi under folded step key (k0,k1).
// JAX partitionable-threefry path (default in modern JAX): counter=(0, vi),
// bits = r0 ^ r1; uniform>0.5 <=> (bits>>9) > 2^22.
// FALLBACK (if a future round shows O(1) absmax, no NaN): legacy path =
//   vi < 110592: bits = r0 of tf(key,(vi, vi+110592))
//   vi >=110592: bits = r1 of tf(key,(vi-110592, vi))
__device__ __forceinline__ float mask_val(uint32_t k0, uint32_t k1, uint32_t vi) {
  uint32_t r0, r1;
  tf2x32(k0, k1, 0u, vi, r0, r1);
  uint32_t bits = r0 ^ r1;
  return ((bits >> 9) > 0x400000u) ? 1.0f : 0.0f;
}

// ---------- dtype detector ----------
// Examine first 256 u32 words of x (values ~ N(0,1)).
// If x is bf16-packed: low u16 of each word is a bf16 sample -> its exponent
// field ((w>>7)&0xFF) concentrates in [110,140] (>99% of words).
// If x is f32: low u16 is uniform mantissa bits -> ~12% in range.
__global__ void nca_detect(const uint32_t* __restrict__ x, uint32_t* __restrict__ flag) {
  __shared__ int cnt[256];
  uint32_t w = x[threadIdx.x];
  uint32_t e = (w >> 7) & 0xFFu;
  cnt[threadIdx.x] = (e >= 110u && e <= 140u) ? 1 : 0;
  __syncthreads();
  for (int s = 128; s > 0; s >>= 1) {
    if ((int)threadIdx.x < s) cnt[threadIdx.x] += cnt[threadIdx.x + s];
    __syncthreads();
  }
  if (threadIdx.x == 0) *flag = (cnt[0] >= 160) ? 1u : 0u;
}

// ---------- weight prep: input dtype -> f32 (+layout transforms) ----------
__global__ __launch_bounds__(256) void nca_prep(
    const void* __restrict__ cw, const void* __restrict__ cb,
    const void* __restrict__ f0w, const void* __restrict__ f0b,
    const void* __restrict__ f1w, float* __restrict__ wb,
    const uint32_t* __restrict__ flagp) {
  uint32_t bf = *flagp;
  int e = blockIdx.x * 256 + threadIdx.x;
  if (e < 6912) {
    // cwT[t*256 + i*16 + o] = conv_w[o][i][t], t = kx*9+ky*3+kz
    int t = e >> 8, r = e & 255, i = r >> 4, o = r & 15;
    wb[W_CWT + e] = ldin(cw, o * 432 + i * 27 + t, bf);
  } else if (e < 6928) {
    wb[W_CB + (e - 6912)] = ldin(cb, e - 6912, bf);
  } else if (e < 13072) {
    wb[W_F0W + (e - 6928)] = ldin(f0w, e - 6928, bf);   // (128,48) row-major as-is
  } else if (e < 13200) {
    wb[W_F0B + (e - 13072)] = ldin(f0b, e - 13072, bf);
  } else if (e < W_TOT) {
    int r = e - 13200, c = r / 128, k = r % 128;         // fc1_w (32,128) -> f1T[k][c]
    wb[W_F1T + k * 32 + c] = ldin(f1w, r, bf);
  }
}

// ---------- init: state ch0..15 = x, ch16..31 = 0 ----------
__global__ __launch_bounds__(256) void nca_init(const void* __restrict__ x,
                                                float* __restrict__ st,
                                                const uint32_t* __restrict__ flagp) {
  uint32_t bf = *flagp;
  int gid = blockIdx.x * 256 + threadIdx.x;          // one voxel
  float v[32];
#pragma unroll
  for (int c = 0; c < 16; c++) v[c] = ldin(x, gid * 16 + c, bf);
#pragma unroll
  for (int c = 16; c < 32; c++) v[c] = 0.0f;
  float* po = st + (size_t)gid * 32;
#pragma unroll
  for (int c = 0; c < 32; c += 4)
    *(float4*)(po + c) = make_float4(v[c], v[c + 1], v[c + 2], v[c + 3]);
}

// ---------- one NCA step: conv(16->16,3^3,reflect) + fc0(48->128,relu) + fc1(128->32)
//            + stochastic residual, channel 0 frozen. Thread per voxel, pure f32. ----------
__global__ __launch_bounds__(256) void nca_step(
    const float* __restrict__ sin, float* __restrict__ sout,
    const float* __restrict__ wb, uint32_t k0, uint32_t k1) {
  int gid = blockIdx.x * 256 + threadIdx.x;
  int w  = gid % 48;
  int t1 = gid / 48;
  int h  = t1 % 48;
  int t2 = t1 / 48;
  int d  = t2 % 48;
  int b  = t2 / 48;

  const float* cwT = wb + W_CWT;
  const float* cbv = wb + W_CB;
  const float* f0w = wb + W_F0W;
  const float* f0b = wb + W_F0B;
  const float* f1T = wb + W_F1T;

  // din = [xc(16) | conv(16) | xm(16)]
  float din[48];
  const float* own = sin + (size_t)gid * 32;
#pragma unroll
  for (int c = 0; c < 16; c += 4) {
    float4 v = *(const float4*)(own + c);
    din[c] = v.x; din[c + 1] = v.y; din[c + 2] = v.z; din[c + 3] = v.w;
  }
#pragma unroll
  for (int c = 0; c < 16; c += 4) {
    float4 v = *(const float4*)(own + 16 + c);
    din[32 + c] = v.x; din[33 + c] = v.y; din[34 + c] = v.z; din[35 + c] = v.w;
  }
#pragma unroll
  for (int o = 0; o < 16; o++) din[16 + o] = cbv[o];

  // reflect indices for +-1 (pad=1, mode='reflect': -1 -> 1, 48 -> 46)
  int dm = (d == 0) ? 1 : d - 1, dp = (d == 47) ? 46 : d + 1;
  int hm = (h == 0) ? 1 : h - 1, hp = (h == 47) ? 46 : h + 1;
  int wm = (w == 0) ? 1 : w - 1, wp = (w == 47) ? 46 : w + 1;

  for (int t = 0; t < 27; t++) {           // t = kx*9 + ky*3 + kz; kx->h, ky->w, kz->d
    int kz = t % 3, rr = t / 3, ky = rr % 3, kx = rr / 3;
    int dd = (kz == 0) ? dm : ((kz == 1) ? d : dp);
    int hh = (kx == 0) ? hm : ((kx == 1) ? h : hp);
    int ww = (ky == 0) ? wm : ((ky == 1) ? w : wp);
    const float* nb = sin + ((((size_t)b * 48 + dd) * 48 + hh) * 48 + ww) * 32;
    const float* wt = cwT + t * 256;       // [i][o]
#pragma unroll
    for (int i = 0; i < 16; i += 4) {
      float4 xv = *(const float4*)(nb + i);
#pragma unroll
      for (int o = 0; o < 16; o++) {
        din[16 + o] += wt[(i + 0) * 16 + o] * xv.x;
        din[16 + o] += wt[(i + 1) * 16 + o] * xv.y;
        din[16 + o] += wt[(i + 2) * 16 + o] * xv.z;
        din[16 + o] += wt[(i + 3) * 16 + o] * xv.w;
      }
    }
  }

  // fc0 (relu) fused with fc1 accumulation
  float dx[32];
#pragma unroll
  for (int c = 0; c < 32; c++) dx[c] = 0.0f;
  for (int k = 0; k < 128; k++) {
    const float* w0 = f0w + k * 48;
    float h0 = f0b[k], h1 = 0.0f, h2 = 0.0f, h3 = 0.0f;
#pragma unroll
    for (int c = 0; c < 48; c += 4) {
      h0 += w0[c + 0] * din[c + 0];
      h1 += w0[c + 1] * din[c + 1];
      h2 += w0[c + 2] * din[c + 2];
      h3 += w0[c + 3] * din[c + 3];
    }
    float hk = fmaxf((h0 + h1) + (h2 + h3), 0.0f);
    const float* w1 = f1T + k * 32;
#pragma unroll
    for (int c = 0; c < 32; c++) dx[c] += w1[c] * hk;
  }

  // stochastic residual update; channel 0 frozen to OLD state
  float m = mask_val(k0, k1, (uint32_t)gid);
  float outv[32];
  outv[0] = din[0];
#pragma unroll
  for (int c = 1; c < 16; c++)  outv[c] = fmaf(dx[c], m, din[c]);        // xc part
#pragma unroll
  for (int c = 16; c < 32; c++) outv[c] = fmaf(dx[c], m, din[c + 16]);   // xm part
  float* po = sout + (size_t)gid * 32;
#pragma unroll
  for (int c = 0; c < 32; c += 4)
    *(float4*)(po + c) = make_float4(outv[c], outv[c + 1], outv[c + 2], outv[c + 3]);
}

// ---------- final f32 state -> output (dtype per flag) ----------
__global__ __launch_bounds__(256) void nca_out(const float* __restrict__ st,
                                               void* __restrict__ out,
                                               const uint32_t* __restrict__ flagp) {
  uint32_t bf = *flagp;
  int gid = blockIdx.x * 256 + threadIdx.x;           // 4 elems/thread
  float4 v = *(const float4*)(st + (size_t)gid * 4);
  if (bf) {
    ushort4 u;
    u.x = f2bf(v.x); u.y = f2bf(v.y); u.z = f2bf(v.z); u.w = f2bf(v.w);
    *(ushort4*)((unsigned short*)out + (size_t)gid * 4) = u;
  } else {
    *(float4*)((float*)out + (size_t)gid * 4) = v;
  }
}

extern "C" void kernel_launch(void* const* d_in, const int* in_sizes, int n_in,
                              void* d_out, int out_size, void* d_ws, size_t ws_size,
                              hipStream_t stream) {
  float* ws = (float*)d_ws;
  float* sA = ws;                 // state buffer A (f32, full precision across steps)
  float* sB = ws + NSTATE;        // state buffer B
  float* wb = ws + 2 * NSTATE;    // f32 weights
  uint32_t* flag = (uint32_t*)(ws + 2 * NSTATE + W_TOT);

  nca_detect<<<1, 256, 0, stream>>>((const uint32_t*)d_in[0], flag);
  nca_prep<<<68, 256, 0, stream>>>(d_in[1], d_in[2], d_in[3], d_in[4], d_in[5], wb, flag);
  nca_init<<<NVOX / 256, 256, 0, stream>>>(d_in[0], sA, flag);

  float* src = sA;
  float* dst = sB;
  for (int s = 0; s < 10; s++) {
    // folded step key: threefry2x32(key(42)=(0,42), (0, step)) — host-side, deterministic
    uint32_t o0, o1;
    tf2x32(0u, 42u, 0u, (uint32_t)s, o0, o1);
    nca_step<<<NVOX / 256, 256, 0, stream>>>(src, dst, wb, o0, o1);
    float* tmp = src; src = dst; dst = tmp;
  }
  nca_out<<<NSTATE / 4 / 256, 256, 0, stream>>>(src, d_out, flag);
}

// Round 4
// 2071.985 us; speedup vs baseline: 1.0941x; 1.0941x over previous
//
#include <hip/hip_runtime.h>
#include <stdint.h>

// Problem constants
#define NVOX   221184      // 2*48*48*48 voxels
#define NSTATE 7077888     // NVOX * 32 channels
// ws layout (floats):
//   [0, NSTATE)            stateA (f32)
//   [NSTATE, 2*NSTATE)     stateB (f32)
//   [2*NSTATE, +W_TOT)     weights (f32, transformed layouts)
//   [2*NSTATE + W_TOT]     dtype flag (u32: 1 = inputs bf16-packed, 0 = f32)
#define W_CWT 0
#define W_CB  6912
#define W_F0W 6928
#define W_F0B 13072
#define W_F1T 13200
#define W_TOT 17296

// ---------- bf16 helpers ----------
__host__ __device__ __forceinline__ float bf2f(unsigned short u) {
  union { uint32_t u; float f; } v; v.u = ((uint32_t)u) << 16; return v.f;
}
__device__ __forceinline__ unsigned short f2bf(float f) {  // RNE, finite values
  union { float f; uint32_t u; } v; v.f = f;
  uint32_t r = (v.u + 0x7FFFu + ((v.u >> 16) & 1u)) >> 16;
  return (unsigned short)r;
}
__device__ __forceinline__ float ldin(const void* p, int i, uint32_t bf) {
  return bf ? bf2f(((const unsigned short*)p)[i]) : ((const float*)p)[i];
}

// ---------- JAX Threefry-2x32 (20 rounds), bit-exact ----------
__host__ __device__ __forceinline__ void tf2x32(uint32_t k0, uint32_t k1,
                                                uint32_t x0, uint32_t x1,
                                                uint32_t& o0, uint32_t& o1) {
  uint32_t ks2 = k0 ^ k1 ^ 0x1BD11BDAu;
#define TFR(r) { x0 += x1; x1 = (x1 << r) | (x1 >> (32 - r)); x1 ^= x0; }
  x0 += k0; x1 += k1;
  TFR(13) TFR(15) TFR(26) TFR(6)
  x0 += k1;  x1 += ks2 + 1u;
  TFR(17) TFR(29) TFR(16) TFR(24)
  x0 += ks2; x1 += k0 + 2u;
  TFR(13) TFR(15) TFR(26) TFR(6)
  x0 += k0;  x1 += k1 + 3u;
  TFR(17) TFR(29) TFR(16) TFR(24)
  x0 += k1;  x1 += ks2 + 4u;
  TFR(13) TFR(15) TFR(26) TFR(6)
  x0 += ks2; x1 += k0 + 5u;
#undef TFR
  o0 = x0; o1 = x1;
}

// Partitionable-threefry mask (verified bit-exact in R3): counter=(0,vi),
// bits=r0^r1, keep (no fire) iff (bits>>9) > 2^22.
__device__ __forceinline__ float mask_val(uint32_t k0, uint32_t k1, uint32_t vi) {
  uint32_t r0, r1;
  tf2x32(k0, k1, 0u, vi, r0, r1);
  uint32_t bits = r0 ^ r1;
  return ((bits >> 9) > 0x400000u) ? 1.0f : 0.0f;
}

// ---------- dtype detector (verified in R3: flags f32) ----------
__global__ void nca_detect(const uint32_t* __restrict__ x, uint32_t* __restrict__ flag) {
  __shared__ int cnt[256];
  uint32_t w = x[threadIdx.x];
  uint32_t e = (w >> 7) & 0xFFu;
  cnt[threadIdx.x] = (e >= 110u && e <= 140u) ? 1 : 0;
  __syncthreads();
  for (int s = 128; s > 0; s >>= 1) {
    if ((int)threadIdx.x < s) cnt[threadIdx.x] += cnt[threadIdx.x + s];
    __syncthreads();
  }
  if (threadIdx.x == 0) *flag = (cnt[0] >= 160) ? 1u : 0u;
}

// ---------- weight prep ----------
__global__ __launch_bounds__(256) void nca_prep(
    const void* __restrict__ cw, const void* __restrict__ cb,
    const void* __restrict__ f0w, const void* __restrict__ f0b,
    const void* __restrict__ f1w, float* __restrict__ wb,
    const uint32_t* __restrict__ flagp) {
  uint32_t bf = *flagp;
  int e = blockIdx.x * 256 + threadIdx.x;
  if (e < 6912) {
    // cwT[t*256 + i*16 + o] = conv_w[o][i][t], t = kx*9+ky*3+kz (kx->h, ky->w, kz->d)
    int t = e >> 8, r = e & 255, i = r >> 4, o = r & 15;
    wb[W_CWT + e] = ldin(cw, o * 432 + i * 27 + t, bf);
  } else if (e < 6928) {
    wb[W_CB + (e - 6912)] = ldin(cb, e - 6912, bf);
  } else if (e < 13072) {
    wb[W_F0W + (e - 6928)] = ldin(f0w, e - 6928, bf);   // (128,48) row-major as-is
  } else if (e < 13200) {
    wb[W_F0B + (e - 13072)] = ldin(f0b, e - 13072, bf);
  } else if (e < W_TOT) {
    int r = e - 13200, c = r / 128, k = r % 128;         // fc1_w (32,128) -> f1T[k][c]
    wb[W_F1T + k * 32 + c] = ldin(f1w, r, bf);
  }
}

// ---------- init: state ch0..15 = x, ch16..31 = 0 ----------
__global__ __launch_bounds__(256) void nca_init(const void* __restrict__ x,
                                                float* __restrict__ st,
                                                const uint32_t* __restrict__ flagp) {
  uint32_t bf = *flagp;
  int gid = blockIdx.x * 256 + threadIdx.x;          // one voxel
  float v[32];
#pragma unroll
  for (int c = 0; c < 16; c++) v[c] = ldin(x, gid * 16 + c, bf);
#pragma unroll
  for (int c = 16; c < 32; c++) v[c] = 0.0f;
  float* po = st + (size_t)gid * 32;
#pragma unroll
  for (int c = 0; c < 32; c += 4)
    *(float4*)(po + c) = make_float4(v[c], v[c + 1], v[c + 2], v[c + 3]);
}

// ---------- one NCA step, 3D-tiled for L1 reuse ----------
// Block = 8x8x4 voxel tile (x=w fastest, 256 threads, 1 voxel/thread).
// Conv footprint/block = 10x10x6 lines x 64B = 38 KB, tap loop runs d-offset
// OUTERMOST so the live L1 slab is ~one (h,w) plane (6.4 KB) at a time.
__global__ __launch_bounds__(256) void nca_step(
    const float* __restrict__ sin, float* __restrict__ sout,
    const float* __restrict__ wb, uint32_t k0, uint32_t k1) {
  // block decode: bx = ((b*12 + tz)*6 + ty)*6 + tx
  int bx = blockIdx.x;
  int tx = bx % 6;  int r0 = bx / 6;
  int ty = r0 % 6;  int r1 = r0 / 6;
  int tz = r1 % 12; int b  = r1 / 12;
  int tid = threadIdx.x;
  int x = tid & 7, y = (tid >> 3) & 7, z = tid >> 6;
  int w = tx * 8 + x;
  int h = ty * 8 + y;
  int d = tz * 4 + z;
  int gid = ((b * 48 + d) * 48 + h) * 48 + w;

  const float* cwT = wb + W_CWT;
  const float* cbv = wb + W_CB;
  const float* f0w = wb + W_F0W;
  const float* f0b = wb + W_F0B;
  const float* f1T = wb + W_F1T;

  // din = [xc(16) | conv(16) | xm(16)]
  float din[48];
  const float* own = sin + (size_t)gid * 32;
#pragma unroll
  for (int c = 0; c < 16; c += 4) {
    float4 v = *(const float4*)(own + c);
    din[c] = v.x; din[c + 1] = v.y; din[c + 2] = v.z; din[c + 3] = v.w;
  }
#pragma unroll
  for (int c = 0; c < 16; c += 4) {
    float4 v = *(const float4*)(own + 16 + c);
    din[32 + c] = v.x; din[33 + c] = v.y; din[34 + c] = v.z; din[35 + c] = v.w;
  }
#pragma unroll
  for (int o = 0; o < 16; o++) din[16 + o] = cbv[o];

  // reflect indices (pad=1, mode='reflect': -1 -> 1, 48 -> 46)
  int dn[3], hn[3], wn[3];
  dn[0] = (d == 0) ? 1 : d - 1; dn[1] = d; dn[2] = (d == 47) ? 46 : d + 1;
  hn[0] = (h == 0) ? 1 : h - 1; hn[1] = h; hn[2] = (h == 47) ? 46 : h + 1;
  wn[0] = (w == 0) ? 1 : w - 1; wn[1] = w; wn[2] = (w == 47) ? 46 : w + 1;

  // tap loop: kz (d-offset) OUTER for L1 plane locality; weight tap index
  // t = kx*9 + ky*3 + kz  (kx->h, ky->w, kz->d) — same mapping verified in R3.
  for (int kz = 0; kz < 3; kz++) {
    const float* plane = sin + (((size_t)b * 48 + dn[kz]) * 48) * 48 * 32;
#pragma unroll
    for (int kx = 0; kx < 3; kx++) {
      const float* row = plane + (size_t)hn[kx] * 48 * 32;
#pragma unroll
      for (int ky = 0; ky < 3; ky++) {
        const float* nb = row + (size_t)wn[ky] * 32;
        const float* wt = cwT + (kx * 9 + ky * 3 + kz) * 256;   // [i][o]
#pragma unroll
        for (int i = 0; i < 16; i += 4) {
          float4 xv = *(const float4*)(nb + i);
#pragma unroll
          for (int o = 0; o < 16; o++) {
            din[16 + o] += wt[(i + 0) * 16 + o] * xv.x;
            din[16 + o] += wt[(i + 1) * 16 + o] * xv.y;
            din[16 + o] += wt[(i + 2) * 16 + o] * xv.z;
            din[16 + o] += wt[(i + 3) * 16 + o] * xv.w;
          }
        }
      }
    }
  }

  // fc0 (relu) fused with fc1 accumulation (weights via wave-uniform s_loads)
  float dx[32];
#pragma unroll
  for (int c = 0; c < 32; c++) dx[c] = 0.0f;
  for (int k = 0; k < 128; k++) {
    const float* w0 = f0w + k * 48;
    float h0 = f0b[k], h1 = 0.0f, h2 = 0.0f, h3 = 0.0f;
#pragma unroll
    for (int c = 0; c < 48; c += 4) {
      h0 += w0[c + 0] * din[c + 0];
      h1 += w0[c + 1] * din[c + 1];
      h2 += w0[c + 2] * din[c + 2];
      h3 += w0[c + 3] * din[c + 3];
    }
    float hk = fmaxf((h0 + h1) + (h2 + h3), 0.0f);
    const float* w1 = f1T + k * 32;
#pragma unroll
    for (int c = 0; c < 32; c++) dx[c] += w1[c] * hk;
  }

  // stochastic residual update; channel 0 frozen to OLD state
  float m = mask_val(k0, k1, (uint32_t)gid);
  float outv[32];
  outv[0] = din[0];
#pragma unroll
  for (int c = 1; c < 16; c++)  outv[c] = fmaf(dx[c], m, din[c]);        // xc
#pragma unroll
  for (int c = 16; c < 32; c++) outv[c] = fmaf(dx[c], m, din[c + 16]);   // xm
  float* po = sout + (size_t)gid * 32;
#pragma unroll
  for (int c = 0; c < 32; c += 4)
    *(float4*)(po + c) = make_float4(outv[c], outv[c + 1], outv[c + 2], outv[c + 3]);
}

// ---------- final f32 state -> output (dtype per flag) ----------
__global__ __launch_bounds__(256) void nca_out(const float* __restrict__ st,
                                               void* __restrict__ out,
                                               const uint32_t* __restrict__ flagp) {
  uint32_t bf = *flagp;
  int gid = blockIdx.x * 256 + threadIdx.x;           // 4 elems/thread
  float4 v = *(const float4*)(st + (size_t)gid * 4);
  if (bf) {
    ushort4 u;
    u.x = f2bf(v.x); u.y = f2bf(v.y); u.z = f2bf(v.z); u.w = f2bf(v.w);
    *(ushort4*)((unsigned short*)out + (size_t)gid * 4) = u;
  } else {
    *(float4*)((float*)out + (size_t)gid * 4) = v;
  }
}

extern "C" void kernel_launch(void* const* d_in, const int* in_sizes, int n_in,
                              void* d_out, int out_size, void* d_ws, size_t ws_size,
                              hipStream_t stream) {
  float* ws = (float*)d_ws;
  float* sA = ws;
  float* sB = ws + NSTATE;
  float* wb = ws + 2 * NSTATE;
  uint32_t* flag = (uint32_t*)(ws + 2 * NSTATE + W_TOT);

  nca_detect<<<1, 256, 0, stream>>>((const uint32_t*)d_in[0], flag);
  nca_prep<<<68, 256, 0, stream>>>(d_in[1], d_in[2], d_in[3], d_in[4], d_in[5], wb, flag);
  nca_init<<<NVOX / 256, 256, 0, stream>>>(d_in[0], sA, flag);

  float* src = sA;
  float* dst = sB;
  for (int s = 0; s < 10; s++) {
    uint32_t o0, o1;
    tf2x32(0u, 42u, 0u, (uint32_t)s, o0, o1);   // folded step key, host-side
    nca_step<<<864, 256, 0, stream>>>(src, dst, wb, o0, o1);
    float* tmp = src; src = dst; dst = tmp;
  }
  nca_out<<<NSTATE / 4 / 256, 256, 0, stream>>>(src, d_out, flag);
}